// Round 11
// baseline (189.202 us; speedup 1.0000x reference)
//
#include <hip/hip_runtime.h>

#define NB 32
#define TT 512
#define SS 5
#define CC 512
#define UU 256
#define NEGV -1e30f
#define LCH 16                 // timesteps per chunk
#define NCH (TT / LCH)         // 32 chunks
#define PKW 12                 // packed row width: e0..e3, b0..b4, pad x3
#define NREP 4                 // scan replicas (attribution probe)

// ---------------------------------------------------------------------------
// Kernel A: per-row sum-exp over C=512 (no-max LSE). At HBM roofline
// (~6.1 TB/s measured via round-10 marginal probe). Zeroes NREP counters.
// ---------------------------------------------------------------------------
__global__ __launch_bounds__(512) void row_lse_kernel(
    const float* __restrict__ logits,   // [N][T][S][C]
    const int*   __restrict__ ranges,   // [N][T][S]
    const int*   __restrict__ y,        // [N][U]
    float*       __restrict__ packed,   // [T][N][PKW]
    int*         __restrict__ cnt)      // NREP stage-1 completion counters
{
    if (blockIdx.x == 0 && threadIdx.x < NREP) cnt[threadIdx.x] = 0;

    const int lane = threadIdx.x & 63;
    const int row  = blockIdx.x * 8 + (threadIdx.x >> 6);  // 0..81919
    const float* rowp = logits + (size_t)row * CC;

    float4 a = *(const float4*)(rowp + lane * 4);          // floats [0,256)
    float4 b = *(const float4*)(rowp + 256 + lane * 4);    // floats [256,512)

    float s = __expf(a.x) + __expf(a.y) + __expf(a.z) + __expf(a.w)
            + __expf(b.x) + __expf(b.y) + __expf(b.z) + __expf(b.w);
#pragma unroll
    for (int off = 32; off; off >>= 1)
        s += __shfl_xor(s, off);

    // wave-uniform gather chain (all lanes same address -> single line each)
    const int   rg    = ranges[row];
    const int   n     = row / (TT * SS);
    const int   sy    = y[n * UU + rg];
    const float emraw = rowp[sy];
    const float blraw = rowp[0];
    const float lse   = __logf(s);

    if (lane == 0) {
        int loc  = row - n * (TT * SS);
        int t    = loc / SS;
        int sidx = loc - t * SS;
        float* dst = packed + ((size_t)t * NB + n) * PKW;
        if (sidx < 4) dst[sidx] = emraw - lse;   // em used only for s=0..3
        dst[4 + sidx] = blraw - lse;             // bl for s=0..4
    }
}

// ---------------------------------------------------------------------------
// Semiring helpers. lse(x,y) = max + log1p(exp(-|x-y|)); sel=0 -> max only.
// ---------------------------------------------------------------------------
__device__ __forceinline__ float lse_corr(float x, float y) {
    return __logf(1.0f + __expf(-fabsf(x - y)));
}
__device__ __forceinline__ float combsel(float x, float y, float sel) {
    return fmaxf(x, y) + sel * lse_corr(x, y);
}
template <bool MAXSEM>
__device__ __forceinline__ float combf(float x, float y) {
    return MAXSEM ? fmaxf(x, y) : fmaxf(x, y) + lse_corr(x, y);
}

template <bool MAXSEM>
__device__ __forceinline__ void matvec(const float m[25],
    float& v0, float& v1, float& v2, float& v3, float& v4)
{
    float r0 = combf<MAXSEM>(combf<MAXSEM>(combf<MAXSEM>(combf<MAXSEM>(
                 m[0] + v0, m[5] + v1), m[10] + v2), m[15] + v3), m[20] + v4);
    float r1 = combf<MAXSEM>(combf<MAXSEM>(combf<MAXSEM>(combf<MAXSEM>(
                 m[1] + v0, m[6] + v1), m[11] + v2), m[16] + v3), m[21] + v4);
    float r2 = combf<MAXSEM>(combf<MAXSEM>(combf<MAXSEM>(combf<MAXSEM>(
                 m[2] + v0, m[7] + v1), m[12] + v2), m[17] + v3), m[22] + v4);
    float r3 = combf<MAXSEM>(combf<MAXSEM>(combf<MAXSEM>(combf<MAXSEM>(
                 m[3] + v0, m[8] + v1), m[13] + v2), m[18] + v3), m[23] + v4);
    float r4 = combf<MAXSEM>(combf<MAXSEM>(combf<MAXSEM>(combf<MAXSEM>(
                 m[4] + v0, m[9] + v1), m[14] + v2), m[19] + v3), m[24] + v4);
    v0 = r0; v1 = r1; v2 = r2; v3 = r3; v4 = r4;
}

template <bool MAXSEM>
__device__ __forceinline__ float compose_all(const float* __restrict__ base)
{
    float v0 = 0.0f, v1 = NEGV, v2 = NEGV, v3 = NEGV, v4 = NEGV;
    float mA[25], mB[25];
#pragma unroll
    for (int q = 0; q < 25; ++q) mA[q] = base[q];
    for (int c = 0; c < NCH; c += 2) {
#pragma unroll
        for (int q = 0; q < 25; ++q) mB[q] = base[(size_t)(c + 1) * NB * 25 + q];
        matvec<MAXSEM>(mA, v0, v1, v2, v3, v4);
        if (c + 2 < NCH) {
#pragma unroll
            for (int q = 0; q < 25; ++q) mA[q] = base[(size_t)(c + 2) * NB * 25 + q];
        }
        matvec<MAXSEM>(mB, v0, v1, v2, v3, v4);
    }
    return -v4;
}

// ---------------------------------------------------------------------------
// Kernel B: stage1 (one chunk per block) + stage2 by the LAST finishing block.
// This round launched NREP x with distinct counters (marginal-cost probe).
// ---------------------------------------------------------------------------
__global__ __launch_bounds__(320) void scan_fused(
    const float* __restrict__ packed,   // [T][N][PKW]
    const int*   __restrict__ ranges,   // [N][T][S]
    float*       __restrict__ mats,     // [2][NCH][NB][25]
    int*         __restrict__ cnt,
    float*       __restrict__ out)      // [2]
{
    __shared__ float pk[LCH][NB][PKW];      // 24 KB
    __shared__ int   lbb[LCH + 1][NB];      // 2.1 KB
    __shared__ int   amLast;

    const int tid = threadIdx.x;            // 0..319
    const int c   = blockIdx.x;             // chunk id
    const int t0  = c * LCH;

    // ---- stage 1: chunk -> 5x5 semiring matrix ----
    {   // bulk load packed chunk: 1536 float4
        const float4* gsrc = (const float4*)(packed + (size_t)t0 * NB * PKW);
        float4* ldst = (float4*)&pk[0][0][0];
        float4 a0 = gsrc[tid];
        float4 a1 = gsrc[tid + 320];
        float4 a2 = gsrc[tid + 640];
        float4 a3 = gsrc[tid + 960];
        bool g4 = (tid + 1280) < LCH * NB * 3;
        float4 a4 = a0;
        if (g4) a4 = gsrc[tid + 1280];
        ldst[tid] = a0; ldst[tid + 320] = a1; ldst[tid + 640] = a2;
        ldst[tid + 960] = a3;
        if (g4) ldst[tid + 1280] = a4;
    }
    {   // lb values: (LCH+1)*NB = 544 ints
        int ii = tid >> 5, nn = tid & 31;
        int t = t0 + ii; if (t > TT - 1) t = TT - 1;
        lbb[ii][nn] = ranges[(nn * TT + t) * SS];
        int i1 = tid + 320;
        if (i1 < (LCH + 1) * NB) {
            int ii1 = i1 >> 5, nn1 = i1 & 31;
            int t1 = t0 + ii1; if (t1 > TT - 1) t1 = TT - 1;
            lbb[ii1][nn1] = ranges[(nn1 * TT + t1) * SS];
        }
    }
    __syncthreads();

    {
        const int   lane = tid & 63;
        const int   n    = lane & 31;
        const int   sem  = lane >> 5;        // 0 = lse, 1 = max
        const float sel  = sem ? 0.0f : 1.0f;
        const int   j    = tid >> 6;         // basis column 0..4

        float v0 = (j == 0) ? 0.0f : NEGV;
        float v1 = (j == 1) ? 0.0f : NEGV;
        float v2 = (j == 2) ? 0.0f : NEGV;
        float v3 = (j == 3) ? 0.0f : NEGV;
        float v4 = (j == 4) ? 0.0f : NEGV;

        for (int i = 0; i < LCH; ++i) {
            int t = t0 + i;
            float e0 = pk[i][n][0], e1 = pk[i][n][1];
            float e2 = pk[i][n][2], e3 = pk[i][n][3];

            v1 = combsel(v1, v0 + e0, sel);
            v2 = combsel(v2, v1 + e1, sel);
            v3 = combsel(v3, v2 + e2, sel);
            v4 = combsel(v4, v3 + e3, sel);

            if (t < TT - 1) {                        // wave-uniform
                float b0 = pk[i][n][4], b1 = pk[i][n][5], b2 = pk[i][n][6];
                float b3 = pk[i][n][7], b4 = pk[i][n][8];
                bool sh = lbb[i + 1][n] != lbb[i][n];    // delta in {0,1}
                float n0 = sh ? v1 + b1 : v0 + b0;
                float n1 = sh ? v2 + b2 : v1 + b1;
                float n2 = sh ? v3 + b3 : v2 + b2;
                float n3 = sh ? v4 + b4 : v3 + b3;
                float n4 = sh ? NEGV    : v4 + b4;
                v0 = n0; v1 = n1; v2 = n2; v3 = n3; v4 = n4;
            }
        }

        float* outp = mats + (((size_t)sem * NCH + c) * NB + n) * 25 + j * 5;
        outp[0] = v0; outp[1] = v1; outp[2] = v2; outp[3] = v3; outp[4] = v4;
    }

    // ---- completion protocol: last finishing block runs stage 2 ----
    __syncthreads();                 // all waves' mats stores issued
    __threadfence();                 // release: flush to device scope
    if (tid == 0) {
        int old = __hip_atomic_fetch_add(cnt, 1, __ATOMIC_ACQ_REL,
                                         __HIP_MEMORY_SCOPE_AGENT);
        amLast = (old == NCH - 1);
    }
    __syncthreads();
    if (!amLast || tid >= 128) return;

    // ---- stage 2 (last block only, waves 0-1) ----
    {
        int  sem  = tid >> 6;            // wave 0: lse, wave 1: max
        int  lane = tid & 63;
        bool act  = lane < NB;
        int  n    = lane & 31;

        const float* base = mats + ((size_t)sem * NCH * NB + n) * 25;
        float p = (sem == 0) ? compose_all<false>(base)
                             : compose_all<true >(base);
        if (!act) p = 0.0f;

#pragma unroll
        for (int off = 16; off; off >>= 1)
            p += __shfl_xor(p, off);
        if (lane == 0) out[sem] = p;   // out[0]=pruned, out[1]=one_best
    }
}

extern "C" void kernel_launch(void* const* d_in, const int* in_sizes, int n_in,
                              void* d_out, int out_size, void* d_ws, size_t ws_size,
                              hipStream_t stream) {
    const float* logits = (const float*)d_in[0];
    const int*   ranges = (const int*)d_in[1];
    const int*   y      = (const int*)d_in[2];
    // d_in[3] = x_lens, unused (reference ignores it; all == T)

    float* packed = (float*)d_ws;                       // T*N*PKW floats
    float* mats   = packed + (size_t)TT * NB * PKW;     // 2*NCH*NB*25 floats
    int*   cnt    = (int*)(mats + (size_t)2 * NCH * NB * 25);  // NREP ints
    float* out    = (float*)d_out;

    int rows = NB * TT * SS;                            // 81920
    hipLaunchKernelGGL(row_lse_kernel, dim3(rows / 8), dim3(512), 0, stream,
                       logits, ranges, y, packed, cnt);
    // ATTRIBUTION PROBE: NREP idempotent scan launches, distinct counters.
    // dur_us = dur_r9 + (NREP-1) * t_scan  ->  timed-path cost of the scan.
    for (int rep = 0; rep < NREP; ++rep) {
        hipLaunchKernelGGL(scan_fused, dim3(NCH), dim3(320), 0, stream,
                           packed, ranges, mats, cnt + rep, out);
    }
}

// Round 12
// 49.664 us; speedup vs baseline: 3.8097x; 3.8097x over previous
//
#include <hip/hip_runtime.h>

#define NB 32
#define TT 512
#define SS 5
#define CC 512
#define UU 256
#define NEGV -1e30f
#define LCH 8                  // timesteps per chunk (was 16)
#define NCH (TT / LCH)         // 64 chunks
#define PKW 12                 // packed row width: e0..e3, b0..b4, pad x3
#define TREEB (2 * NB)         // 64 tree blocks: one per (n, sem)

// ---------------------------------------------------------------------------
// Kernel A: per-row sum-exp over C=512 (no-max LSE). At HBM roofline
// (~6.1 TB/s, round-10 marginal probe). Zeroes the tree completion counter.
// ---------------------------------------------------------------------------
__global__ __launch_bounds__(512) void row_lse_kernel(
    const float* __restrict__ logits,   // [N][T][S][C]
    const int*   __restrict__ ranges,   // [N][T][S]
    const int*   __restrict__ y,        // [N][U]
    float*       __restrict__ packed,   // [T][N][PKW]
    int*         __restrict__ cnt)      // tree completion counter
{
    if (blockIdx.x == 0 && threadIdx.x == 0) *cnt = 0;

    const int lane = threadIdx.x & 63;
    const int row  = blockIdx.x * 8 + (threadIdx.x >> 6);  // 0..81919
    const float* rowp = logits + (size_t)row * CC;

    float4 a = *(const float4*)(rowp + lane * 4);          // floats [0,256)
    float4 b = *(const float4*)(rowp + 256 + lane * 4);    // floats [256,512)

    float s = __expf(a.x) + __expf(a.y) + __expf(a.z) + __expf(a.w)
            + __expf(b.x) + __expf(b.y) + __expf(b.z) + __expf(b.w);
#pragma unroll
    for (int off = 32; off; off >>= 1)
        s += __shfl_xor(s, off);

    const int   rg    = ranges[row];
    const int   n     = row / (TT * SS);
    const int   sy    = y[n * UU + rg];
    const float emraw = rowp[sy];
    const float blraw = rowp[0];
    const float lse   = __logf(s);

    if (lane == 0) {
        int loc  = row - n * (TT * SS);
        int t    = loc / SS;
        int sidx = loc - t * SS;
        float* dst = packed + ((size_t)t * NB + n) * PKW;
        if (sidx < 4) dst[sidx] = emraw - lse;   // em used only for s=0..3
        dst[4 + sidx] = blraw - lse;             // bl for s=0..4
    }
}

// ---------------------------------------------------------------------------
// Semiring helpers.
// ---------------------------------------------------------------------------
__device__ __forceinline__ float lse_corr(float x, float y) {
    return __logf(1.0f + __expf(-fabsf(x - y)));
}
__device__ __forceinline__ float combsel(float x, float y, float sel) {
    return fmaxf(x, y) + sel * lse_corr(x, y);
}
template <bool MAXSEM>
__device__ __forceinline__ float combf(float x, float y) {
    return MAXSEM ? fmaxf(x, y) : fmaxf(x, y) + lse_corr(x, y);
}
// tree-fold of 5 (depth 3 instead of 4)
template <bool MAXSEM>
__device__ __forceinline__ float fold5(float t0, float t1, float t2,
                                       float t3, float t4) {
    float c01 = combf<MAXSEM>(t0, t1);
    float c23 = combf<MAXSEM>(t2, t3);
    return combf<MAXSEM>(combf<MAXSEM>(c01, c23), t4);
}

// ---------------------------------------------------------------------------
// Stage 1: chunk -> 5x5 semiring matrix. 64 blocks x 320 threads.
// mats layout: [sem][c][n][25], entry j*5+s = M_c[s][j].
// ---------------------------------------------------------------------------
__global__ __launch_bounds__(320) void scan_stage1(
    const float* __restrict__ packed,   // [T][N][PKW]
    const int*   __restrict__ ranges,   // [N][T][S]
    float*       __restrict__ mats)
{
    __shared__ float pk[LCH][NB][PKW];      // 12 KB
    __shared__ int   lbb[LCH + 1][NB];      // 1.2 KB

    const int tid = threadIdx.x;            // 0..319
    const int c   = blockIdx.x;             // 0..NCH-1
    const int t0  = c * LCH;

    {   // bulk load packed chunk: 768 float4
        const float4* gsrc = (const float4*)(packed + (size_t)t0 * NB * PKW);
        float4* ldst = (float4*)&pk[0][0][0];
        float4 a0 = gsrc[tid];
        float4 a1 = gsrc[tid + 320];
        bool g2 = (tid + 640) < LCH * NB * 3;
        float4 a2 = a0;
        if (g2) a2 = gsrc[tid + 640];
        ldst[tid] = a0; ldst[tid + 320] = a1;
        if (g2) ldst[tid + 640] = a2;
    }
    if (tid < (LCH + 1) * NB) {   // 288 lb values
        int ii = tid >> 5, nn = tid & 31;
        int t = t0 + ii; if (t > TT - 1) t = TT - 1;
        lbb[ii][nn] = ranges[(nn * TT + t) * SS];
    }
    __syncthreads();

    const int   lane = tid & 63;
    const int   n    = lane & 31;
    const int   sem  = lane >> 5;        // 0 = lse, 1 = max
    const float sel  = sem ? 0.0f : 1.0f;
    const int   j    = tid >> 6;         // basis column 0..4

    float v0 = (j == 0) ? 0.0f : NEGV;
    float v1 = (j == 1) ? 0.0f : NEGV;
    float v2 = (j == 2) ? 0.0f : NEGV;
    float v3 = (j == 3) ? 0.0f : NEGV;
    float v4 = (j == 4) ? 0.0f : NEGV;

    for (int i = 0; i < LCH; ++i) {
        int t = t0 + i;
        float e0 = pk[i][n][0], e1 = pk[i][n][1];
        float e2 = pk[i][n][2], e3 = pk[i][n][3];

        v1 = combsel(v1, v0 + e0, sel);
        v2 = combsel(v2, v1 + e1, sel);
        v3 = combsel(v3, v2 + e2, sel);
        v4 = combsel(v4, v3 + e3, sel);

        if (t < TT - 1) {                        // wave-uniform
            float b0 = pk[i][n][4], b1 = pk[i][n][5], b2 = pk[i][n][6];
            float b3 = pk[i][n][7], b4 = pk[i][n][8];
            bool sh = lbb[i + 1][n] != lbb[i][n];    // delta in {0,1}
            float n0 = sh ? v1 + b1 : v0 + b0;
            float n1 = sh ? v2 + b2 : v1 + b1;
            float n2 = sh ? v3 + b3 : v2 + b2;
            float n3 = sh ? v4 + b4 : v3 + b3;
            float n4 = sh ? NEGV    : v4 + b4;
            v0 = n0; v1 = n1; v2 = n2; v3 = n3; v4 = n4;
        }
    }

    float* outp = mats + (((size_t)sem * NCH + c) * NB + n) * 25 + j * 5;
    outp[0] = v0; outp[1] = v1; outp[2] = v2; outp[3] = v3; outp[4] = v4;
}

// ---------------------------------------------------------------------------
// Tree kernel: per (n,sem) block, pairwise-compose 64 chunk matrices in LDS.
// (B (.) A)[s][j] = comb_q (B[s][q] + A[q][j]);   col-major m[j*5+s].
// Answer = -M_tot[4][0]. Last block sums the 64 partials -> out[2].
// ---------------------------------------------------------------------------
template <bool MAXSEM>
__device__ __forceinline__ void tree_run(
    const float* __restrict__ gsrc,   // mats + sem*NCH*NB*25
    float* __restrict__ bufA, float* __restrict__ bufB,
    float* __restrict__ partials, int n, int bid)
{
    const int tid = threadIdx.x;

    // load 64 matrices for this n: 1600 floats
    for (int idx = tid; idx < NCH * 25; idx += 256) {
        int c = idx / 25, q = idx - c * 25;
        bufA[idx] = gsrc[((size_t)c * NB + n) * 25 + q];
    }
    __syncthreads();

    float* src = bufA;
    float* dst = bufB;
    int m = NCH;
    while (m > 1) {
        int pairs = m >> 1;
        for (int item = tid; item < pairs * 25; item += 256) {
            int p = item / 25, e = item - p * 25;
            int j = e / 5, s = e - j * 5;
            const float* A = src + (2 * p) * 25;       // earlier chunk
            const float* B = src + (2 * p + 1) * 25;   // later chunk
            float t0 = B[s]      + A[j * 5 + 0];
            float t1 = B[5 + s]  + A[j * 5 + 1];
            float t2 = B[10 + s] + A[j * 5 + 2];
            float t3 = B[15 + s] + A[j * 5 + 3];
            float t4 = B[20 + s] + A[j * 5 + 4];
            dst[item] = fold5<MAXSEM>(t0, t1, t2, t3, t4);
        }
        __syncthreads();
        float* tmp = src; src = dst; dst = tmp;
        m = pairs;
    }
    // src[0..24] = M_tot (col-major); v_init = e0 -> answer = -M_tot[4][0]
    if (tid == 0) partials[bid] = -src[4];
}

__global__ __launch_bounds__(256) void scan_tree(
    const float* __restrict__ mats,     // [2][NCH][NB][25]
    float*       __restrict__ partials, // [TREEB]
    int*         __restrict__ cnt,
    float*       __restrict__ out)      // [2]
{
    __shared__ float bufA[NCH * 25];        // 6.4 KB
    __shared__ float bufB[(NCH / 2) * 25];  // 3.2 KB
    __shared__ int   amLast;

    const int bid = blockIdx.x;             // 0..63
    const int n   = bid & 31;
    const int sem = bid >> 5;                // 0 = lse, 1 = max

    const float* gsrc = mats + (size_t)sem * NCH * NB * 25;
    if (sem == 0) tree_run<false>(gsrc, bufA, bufB, partials, n, bid);
    else          tree_run<true >(gsrc, bufA, bufB, partials, n, bid);

    // completion: last finishing block sums the partials
    __syncthreads();
    __threadfence();
    if (threadIdx.x == 0) {
        int old = __hip_atomic_fetch_add(cnt, 1, __ATOMIC_ACQ_REL,
                                         __HIP_MEMORY_SCOPE_AGENT);
        amLast = (old == TREEB - 1);
    }
    __syncthreads();
    if (!amLast) return;
    __threadfence();                         // reader-side acquire

    if (threadIdx.x < 64) {
        float v = partials[threadIdx.x];     // lanes 0-31: lse, 32-63: max
#pragma unroll
        for (int off = 16; off; off >>= 1)
            v += __shfl_xor(v, off);
        if ((threadIdx.x & 31) == 0)
            out[threadIdx.x >> 5] = v;       // out[0]=pruned, out[1]=one_best
    }
}

extern "C" void kernel_launch(void* const* d_in, const int* in_sizes, int n_in,
                              void* d_out, int out_size, void* d_ws, size_t ws_size,
                              hipStream_t stream) {
    const float* logits = (const float*)d_in[0];
    const int*   ranges = (const int*)d_in[1];
    const int*   y      = (const int*)d_in[2];
    // d_in[3] = x_lens, unused (reference ignores it; all == T)

    float* packed   = (float*)d_ws;                         // TT*NB*PKW
    float* mats     = packed + (size_t)TT * NB * PKW;       // 2*NCH*NB*25
    float* partials = mats + (size_t)2 * NCH * NB * 25;     // TREEB
    int*   cnt      = (int*)(partials + TREEB);             // 1
    float* out      = (float*)d_out;

    int rows = NB * TT * SS;                                // 81920
    hipLaunchKernelGGL(row_lse_kernel, dim3(rows / 8), dim3(512), 0, stream,
                       logits, ranges, y, packed, cnt);
    hipLaunchKernelGGL(scan_stage1, dim3(NCH), dim3(320), 0, stream,
                       packed, ranges, mats);
    hipLaunchKernelGGL(scan_tree, dim3(TREEB), dim3(256), 0, stream,
                       mats, partials, cnt, out);
}